// Round 1
// baseline (2233.291 us; speedup 1.0000x reference)
//
#include <hip/hip_runtime.h>
#include <hip/hip_bf16.h>
#include <math.h>

// MoE: B=16,S=4096 -> T=65536 tokens, D=512, H=1024, E=8, TOP_K=2.
// Dispatch-based: gate fp32 (selection fidelity), experts bf16 MFMA.

typedef __attribute__((ext_vector_type(8))) short bf16x8;
typedef __attribute__((ext_vector_type(4))) float f32x4;

__device__ __forceinline__ unsigned short f2bf(float f){
  unsigned u = __builtin_bit_cast(unsigned, f);
  u += 0x7FFFu + ((u >> 16) & 1u);          // RNE
  return (unsigned short)(u >> 16);
}

__device__ __forceinline__ bf16x8 cvt8(float4 f0, float4 f1){
  bf16x8 r;
  r[0]=(short)f2bf(f0.x); r[1]=(short)f2bf(f0.y); r[2]=(short)f2bf(f0.z); r[3]=(short)f2bf(f0.w);
  r[4]=(short)f2bf(f1.x); r[5]=(short)f2bf(f1.y); r[6]=(short)f2bf(f1.z); r[7]=(short)f2bf(f1.w);
  return r;
}

// ---------------------------------------------------------------------------
// Transpose + fp32->bf16 convert:  in [E][R][C] f32  ->  out [E][C][R] bf16
// ---------------------------------------------------------------------------
__global__ __launch_bounds__(256, 4)
void transpose_cvt_kernel(const float* __restrict__ in, unsigned short* __restrict__ out,
                          int R, int C){
  const int tilesR = R >> 6, tilesC = C >> 6;
  const int b = blockIdx.x;
  const int e = b / (tilesR * tilesC);
  const int rem = b % (tilesR * tilesC);
  const int rb = (rem / tilesC) << 6;
  const int cb = (rem % tilesC) << 6;
  const float* src = in + (size_t)e * R * C;
  unsigned short* dst = out + (size_t)e * R * C;
  __shared__ float t[64][65];
  const int r0 = threadIdx.x >> 4;
  const int c4 = (threadIdx.x & 15) << 2;
  #pragma unroll
  for (int p = 0; p < 4; ++p){
    int r = r0 + (p << 4);
    const float4 v = *(const float4*)(src + (size_t)(rb + r) * C + cb + c4);
    t[r][c4+0] = v.x; t[r][c4+1] = v.y; t[r][c4+2] = v.z; t[r][c4+3] = v.w;
  }
  __syncthreads();
  #pragma unroll
  for (int p = 0; p < 4; ++p){
    int cr = r0 + (p << 4);                 // output row = original col
    ushort4 o;
    o.x = f2bf(t[c4+0][cr]); o.y = f2bf(t[c4+1][cr]);
    o.z = f2bf(t[c4+2][cr]); o.w = f2bf(t[c4+3][cr]);
    *(ushort4*)(dst + (size_t)(cb + cr) * R + rb + c4) = o;
  }
}

// ---------------------------------------------------------------------------
// Gate: fp32 GEMM1(512->256)+relu, GEMM2(256->8), softmax, top2, re-softmax.
// Block = 64 tokens, 256 threads. thread(ty=tid/16, tx=tid&15):
//   tokens ty*4..+3, hidden cols { j*64 + tx*4 + i : j<4, i<4 }.
// ---------------------------------------------------------------------------
__global__ __launch_bounds__(256, 4)
void gate_kernel(const float* __restrict__ x, const float* __restrict__ gw1,
                 const float* __restrict__ gb1, const float* __restrict__ gw2,
                 const float* __restrict__ gb2,
                 int* __restrict__ counts, int* __restrict__ pair_tok,
                 float* __restrict__ pair_w){
  __shared__ float xs[64][17];
  __shared__ float g1s[16][256];
  __shared__ float g2s[256 * 9];
  __shared__ float b1s[256];
  const int tid = threadIdx.x;
  const int t0 = blockIdx.x << 6;
  const int ty = tid >> 4, tx = tid & 15;

  #pragma unroll
  for (int p = 0; p < 8; ++p){
    int idx = tid + (p << 8);               // 0..2047
    g2s[(idx >> 3) * 9 + (idx & 7)] = gw2[idx];
  }
  b1s[tid] = gb1[tid];

  float acc[4][16];
  #pragma unroll
  for (int t = 0; t < 4; ++t)
    #pragma unroll
    for (int j = 0; j < 16; ++j) acc[t][j] = 0.f;

  for (int kb = 0; kb < 512; kb += 16){
    { // stage x tile 64x16
      int r = tid >> 2, c = (tid & 3) << 2;
      const float4 v = *(const float4*)(x + (size_t)(t0 + r) * 512 + kb + c);
      xs[r][c+0] = v.x; xs[r][c+1] = v.y; xs[r][c+2] = v.z; xs[r][c+3] = v.w;
    }
    #pragma unroll
    for (int p = 0; p < 4; ++p){ // stage gw1 tile 16x256
      int f = tid + (p << 8);
      int r = f >> 6, c = (f & 63) << 2;
      *(float4*)&g1s[r][c] = *(const float4*)(gw1 + (size_t)(kb + r) * 256 + c);
    }
    __syncthreads();
    #pragma unroll
    for (int k = 0; k < 16; ++k){
      float xv[4];
      #pragma unroll
      for (int t = 0; t < 4; ++t) xv[t] = xs[(ty << 2) + t][k];
      #pragma unroll
      for (int j = 0; j < 4; ++j){
        const float4 wv = *(const float4*)&g1s[k][(j << 6) + (tx << 2)];
        #pragma unroll
        for (int t = 0; t < 4; ++t){
          acc[t][j*4+0] = fmaf(xv[t], wv.x, acc[t][j*4+0]);
          acc[t][j*4+1] = fmaf(xv[t], wv.y, acc[t][j*4+1]);
          acc[t][j*4+2] = fmaf(xv[t], wv.z, acc[t][j*4+2]);
          acc[t][j*4+3] = fmaf(xv[t], wv.w, acc[t][j*4+3]);
        }
      }
    }
    __syncthreads();
  }

  // relu+bias, GEMM2 partials
  float pl[4][8];
  #pragma unroll
  for (int t = 0; t < 4; ++t)
    #pragma unroll
    for (int e = 0; e < 8; ++e) pl[t][e] = 0.f;
  #pragma unroll
  for (int j = 0; j < 4; ++j)
    #pragma unroll
    for (int i = 0; i < 4; ++i){
      int col = (j << 6) + (tx << 2) + i;
      #pragma unroll
      for (int t = 0; t < 4; ++t){
        float h = fmaxf(acc[t][j*4+i] + b1s[col], 0.f);
        #pragma unroll
        for (int e = 0; e < 8; ++e)
          pl[t][e] = fmaf(h, g2s[col * 9 + e], pl[t][e]);
      }
    }
  // reduce across tx (16 lanes)
  #pragma unroll
  for (int m = 1; m <= 8; m <<= 1)
    #pragma unroll
    for (int t = 0; t < 4; ++t)
      #pragma unroll
      for (int e = 0; e < 8; ++e)
        pl[t][e] += __shfl_xor(pl[t][e], m, 64);

  if (tx == 0){
    #pragma unroll
    for (int t = 0; t < 4; ++t){
      int token = t0 + (ty << 2) + t;
      float lg[8];
      #pragma unroll
      for (int e = 0; e < 8; ++e) lg[e] = pl[t][e] + gb2[e];
      float m = lg[0];
      #pragma unroll
      for (int e = 1; e < 8; ++e) m = fmaxf(m, lg[e]);
      float p[8]; float s = 0.f;
      #pragma unroll
      for (int e = 0; e < 8; ++e){ p[e] = expf(lg[e] - m); s += p[e]; }
      float inv = 1.f / s;
      float m1 = -1.f, m2 = -1.f; int i1 = 0, i2 = 0;
      #pragma unroll
      for (int e = 0; e < 8; ++e){
        float pe = p[e] * inv;
        if (pe > m1){ m2 = m1; i2 = i1; m1 = pe; i1 = e; }
        else if (pe > m2){ m2 = pe; i2 = e; }
      }
      // re-softmax over the two top probabilities
      float e21 = expf(m2 - m1);
      float w1 = 1.f / (1.f + e21);
      float w2 = 1.f - w1;
      int pos1 = atomicAdd(&counts[i1], 1);
      pair_tok[(i1 << 16) + pos1] = token; pair_w[(i1 << 16) + pos1] = w1;
      int pos2 = atomicAdd(&counts[i2], 1);
      pair_tok[(i2 << 16) + pos2] = token; pair_w[(i2 << 16) + pos2] = w2;
    }
  }
}

// ---------------------------------------------------------------------------
// Expert MLP: block = expert e x 64 gathered tokens, 256 thr (4 waves x 16 rows).
// A (x rows, K=512) register-resident bf16 frags; loop hc over H in 64-chunks:
//   GEMM1 -> gelu -> hs(LDS, swizzled) -> GEMM2 accumulate [64x512] f32.
// Epilogue: atomicAdd(out, w * (acc + be2)).
// ---------------------------------------------------------------------------
__global__ __launch_bounds__(256, 2)
void expert_kernel(const float* __restrict__ x,
                   const unsigned short* __restrict__ we1T,  // [E][1024][512] bf16
                   const unsigned short* __restrict__ we2T,  // [E][512][1024] bf16
                   const float* __restrict__ be1, const float* __restrict__ be2,
                   const int* __restrict__ counts, const int* __restrict__ pair_tok,
                   const float* __restrict__ pair_w,
                   float* __restrict__ out){
  const int e = blockIdx.x >> 10;
  const int blk = blockIdx.x & 1023;
  const int cnt = counts[e];
  const int base = blk << 6;
  if (base >= cnt) return;
  const int tid = threadIdx.x;
  const int wv = tid >> 6;
  const int lane = tid & 63;
  const int lrow = lane & 15;
  const int kgrp = lane >> 4;

  __shared__ unsigned short w1s[64 * 64];   // [hcol][k] swizzled, 8KB
  __shared__ unsigned short hs [64 * 64];   // [row][k]  swizzled, 8KB
  __shared__ unsigned short w2s[128 * 64];  // [dcol][k] swizzled, 16KB
  char* const w1b = (char*)w1s;
  char* const hsb = (char*)hs;
  char* const w2b = (char*)w2s;

  // A fragments: 16 K-chunks of 32; lane holds x[tok(row=lane&15)][kc*32+kgrp*8 .. +7]
  bf16x8 a[16];
  {
    int r = base + (wv << 4) + lrow;
    int tok = (r < cnt) ? pair_tok[(e << 16) + r] : 0;
    const float* xr = x + (size_t)tok * 512 + (kgrp << 3);
    #pragma unroll
    for (int kc = 0; kc < 16; ++kc){
      const float4 f0 = *(const float4*)(xr + (kc << 5));
      const float4 f1 = *(const float4*)(xr + (kc << 5) + 4);
      a[kc] = cvt8(f0, f1);
    }
  }
  f32x4 acc[32];
  #pragma unroll
  for (int i = 0; i < 32; ++i) acc[i] = (f32x4)0.f;

  const unsigned short* w1g = we1T + ((size_t)e << 19);
  const unsigned short* w2g = we2T + ((size_t)e << 19);

  for (int hc = 0; hc < 1024; hc += 64){
    f32x4 hacc[4];
    #pragma unroll
    for (int i = 0; i < 4; ++i) hacc[i] = (f32x4)0.f;

    #pragma unroll
    for (int kbi = 0; kbi < 8; ++kbi){      // kb = kbi*64, full unroll (a[] static idx)
      { // stage we1T chunk: 64 hcols x 64 k
        int row = tid >> 2, q = tid & 3;
        const unsigned short* sg = w1g + (size_t)(hc + row) * 512 + (kbi << 6) + (q << 4);
        int4 v0 = *(const int4*)(sg);
        int4 v1 = *(const int4*)(sg + 8);
        int b0 = (row << 7) + (q << 5);
        int sw = (row & 7) << 4;
        *(int4*)(w1b + ( b0        ^ sw)) = v0;
        *(int4*)(w1b + ((b0 + 16)  ^ sw)) = v1;
      }
      __syncthreads();
      #pragma unroll
      for (int ct = 0; ct < 4; ++ct){
        int col = (ct << 4) + lrow;
        int sw = (col & 7) << 4;
        #pragma unroll
        for (int k2 = 0; k2 < 2; ++k2){
          int byte = (col << 7) + (k2 << 6) + (kgrp << 4);
          bf16x8 bfr = *(const bf16x8*)(w1b + (byte ^ sw));
          hacc[ct] = __builtin_amdgcn_mfma_f32_16x16x32_bf16(a[kbi*2 + k2], bfr, hacc[ct], 0, 0, 0);
        }
      }
      __syncthreads();
    }
    // bias + exact gelu + store h to LDS (bf16, swizzled)
    #pragma unroll
    for (int ct = 0; ct < 4; ++ct){
      int colL = (ct << 4) + lrow;
      float bias = be1[(e << 10) + hc + colL];
      #pragma unroll
      for (int rr = 0; rr < 4; ++rr){
        int rowL = (wv << 4) + (kgrp << 2) + rr;
        float v = hacc[ct][rr] + bias;
        float g = 0.5f * v * (1.f + erff(v * 0.70710678118654752f));
        int byte = (rowL << 7) + (colL << 1);
        *(unsigned short*)(hsb + (byte ^ ((rowL & 7) << 4))) = f2bf(g);
      }
    }
    __syncthreads();
    bf16x8 a2[2];
    {
      int rowL = (wv << 4) + lrow;
      int sw = (rowL & 7) << 4;
      #pragma unroll
      for (int k2 = 0; k2 < 2; ++k2){
        int byte = (rowL << 7) + (k2 << 6) + (kgrp << 4);
        a2[k2] = *(const bf16x8*)(hsb + (byte ^ sw));
      }
    }
    #pragma unroll
    for (int nb = 0; nb < 4; ++nb){         // full unroll (acc static idx)
      { // stage we2T chunk: 128 dcols x 64 k
        int row = tid >> 1, q = tid & 1;
        const unsigned short* sg = w2g + (size_t)((nb << 7) + row) * 1024 + hc + (q << 5);
        int4 v0 = *(const int4*)(sg);
        int4 v1 = *(const int4*)(sg + 8);
        int4 v2 = *(const int4*)(sg + 16);
        int4 v3 = *(const int4*)(sg + 24);
        int b0 = (row << 7) + (q << 6);
        int sw = (row & 7) << 4;
        *(int4*)(w2b + ( b0        ^ sw)) = v0;
        *(int4*)(w2b + ((b0 + 16)  ^ sw)) = v1;
        *(int4*)(w2b + ((b0 + 32)  ^ sw)) = v2;
        *(int4*)(w2b + ((b0 + 48)  ^ sw)) = v3;
      }
      __syncthreads();
      #pragma unroll
      for (int nt = 0; nt < 8; ++nt){
        int col = (nt << 4) + lrow;
        int sw = (col & 7) << 4;
        #pragma unroll
        for (int k2 = 0; k2 < 2; ++k2){
          int byte = (col << 7) + (k2 << 6) + (kgrp << 4);
          bf16x8 bfr = *(const bf16x8*)(w2b + (byte ^ sw));
          acc[nb*8 + nt] = __builtin_amdgcn_mfma_f32_16x16x32_bf16(a2[k2], bfr, acc[nb*8 + nt], 0, 0, 0);
        }
      }
      __syncthreads();
    }
  }
  // epilogue: weighted atomic accumulate
  #pragma unroll
  for (int rr = 0; rr < 4; ++rr){
    int rowL = (wv << 4) + (kgrp << 2) + rr;
    int rg = base + rowL;
    if (rg < cnt){
      int tok = pair_tok[(e << 16) + rg];
      float wp = pair_w[(e << 16) + rg];
      float* orow = out + (size_t)tok * 512;
      #pragma unroll
      for (int tl = 0; tl < 32; ++tl){
        int col = (tl << 4) + lrow;
        atomicAdd(orow + col, wp * (acc[tl][rr] + be2[(e << 9) + col]));
      }
    }
  }
}

// ---------------------------------------------------------------------------
extern "C" void kernel_launch(void* const* d_in, const int* in_sizes, int n_in,
                              void* d_out, int out_size, void* d_ws, size_t ws_size,
                              hipStream_t stream){
  const float* x   = (const float*)d_in[0];
  const float* gw1 = (const float*)d_in[1];
  const float* gb1 = (const float*)d_in[2];
  const float* gw2 = (const float*)d_in[3];
  const float* gb2 = (const float*)d_in[4];
  const float* we1 = (const float*)d_in[5];
  const float* be1 = (const float*)d_in[6];
  const float* we2 = (const float*)d_in[7];
  const float* be2 = (const float*)d_in[8];
  float* out = (float*)d_out;

  char* ws = (char*)d_ws;
  unsigned short* we1T = (unsigned short*)(ws);                    // 8 MiB
  unsigned short* we2T = (unsigned short*)(ws + 8388608);          // 8 MiB
  int*   counts   = (int*)  (ws + 16777216);                       // 32 B
  int*   pair_tok = (int*)  (ws + 16777472);                       // 2 MiB
  float* pair_w   = (float*)(ws + 16777472 + 2097152);             // 2 MiB

  hipMemsetAsync(d_out, 0, (size_t)out_size * sizeof(float), stream);
  hipMemsetAsync(counts, 0, 32, stream);

  hipLaunchKernelGGL(transpose_cvt_kernel, dim3(1024), dim3(256), 0, stream,
                     we1, we1T, 512, 1024);
  hipLaunchKernelGGL(transpose_cvt_kernel, dim3(1024), dim3(256), 0, stream,
                     we2, we2T, 1024, 512);
  hipLaunchKernelGGL(gate_kernel, dim3(1024), dim3(256), 0, stream,
                     x, gw1, gb1, gw2, gb2, counts, pair_tok, pair_w);
  hipLaunchKernelGGL(expert_kernel, dim3(8192), dim3(256), 0, stream,
                     x, we1T, we2T, be1, be2, counts, pair_tok, pair_w, out);
}